// Round 1
// baseline (338.311 us; speedup 1.0000x reference)
//
#include <hip/hip_runtime.h>
#include <cstdint>

// Problem constants
#define BSZ   16
#define LSEQ  128
#define HS    768
#define NEXP  8          // P
#define MM    1024       // M
#define DD    512        // D
#define TT    (BSZ*LSEQ) // 2048 tokens
#define NPRIV 4

// d_out layout (floats), reference return order:
// obf_word[2048], obf_psr[2048*512], obf_atk[2048*512], ent_loss[1],
// cpy_mask[2048], obf_mask[2048], pri_mask[2048]
#define OFF_WORD 0
#define OFF_PSR  2048
#define OFF_ATK  (2048 + 2048*512)
#define OFF_ENT  (OFF_ATK + 2048*512)
#define OFF_CPY  (OFF_ENT + 1)
#define OFF_OBF  (OFF_CPY + 2048)
#define OFF_PRI  (OFF_OBF + 2048)

// workspace byte offsets
#define WS_SPT      0                       // [TT][MM] f32: logits, then spt in place
#define WS_TOKLIST  (TT*MM*4)               // [NEXP][TT] int
#define WS_CNT      (WS_TOKLIST + NEXP*TT*4)// [NEXP] int
#define WS_ENTSUM   (WS_CNT + NEXP*4)       // [NEXP] f32

// ---------------- K0: bucket tokens by expert ----------------
__global__ void k_bucket(const int* __restrict__ pos,
                         int* __restrict__ toklist, int* __restrict__ cnt)
{
  int t = blockIdx.x * blockDim.x + threadIdx.x;
  if (t >= TT) return;
  int p = pos[t];
  if (p < NEXP) {
    int r = atomicAdd(&cnt[p], 1);
    toklist[p * TT + r] = t;
  }
}

// ---------------- K1: per-expert decode GEMM  logits = ctx_sel @ dec_W[p] + b ----------------
#define TM1 32
#define TN1 128
#define TK1 64

__global__ __launch_bounds__(256) void k_decode(
    const float* __restrict__ ctx, const float* __restrict__ dec_W,
    const float* __restrict__ dec_b, const int* __restrict__ toklist,
    const int* __restrict__ cnt, float* __restrict__ logits)
{
  const int p = blockIdx.z;
  const int ncnt = cnt[p];
  const int row0 = blockIdx.y * TM1;
  if (row0 >= ncnt) return;
  const int n0 = blockIdx.x * TN1;
  const int tid = threadIdx.x;

  __shared__ float sA[TM1][TK1 + 1];  // pad -> bank-spread on token-major reads
  __shared__ float sB[TK1][TN1];

  const int tx = tid & 31, ty = tid >> 5;
  const int tx4 = tx * 4, ty4 = ty * 4;

  // A staging: 32 rows x 64 floats, each thread 8 consecutive floats
  const int ar = tid >> 3;
  const int ac0 = (tid & 7) * 8;
  int tA = -1;
  if (row0 + ar < ncnt) tA = toklist[p * TT + row0 + ar];

  // B staging: 64 rows x 128 floats as float4
  const int br = tid >> 5;
  const int bc4 = (tid & 31) * 4;

  // output token ids
  int tO[4];
  #pragma unroll
  for (int i = 0; i < 4; ++i) {
    int rr = row0 + ty4 + i;
    tO[i] = (rr < ncnt) ? toklist[p * TT + rr] : -1;
  }

  float acc[4][4] = {};

  for (int k0 = 0; k0 < HS; k0 += TK1) {
    if (tA >= 0) {
      const float* src = ctx + (size_t)tA * HS + k0 + ac0;
      #pragma unroll
      for (int j = 0; j < 8; ++j) sA[ar][ac0 + j] = src[j];
    } else {
      #pragma unroll
      for (int j = 0; j < 8; ++j) sA[ar][ac0 + j] = 0.f;
    }
    const float* wbase = dec_W + ((size_t)p * HS + k0) * MM + n0;
    #pragma unroll
    for (int j = 0; j < 8; ++j) {
      *(float4*)&sB[br + j * 8][bc4] =
          *(const float4*)(wbase + (size_t)(br + j * 8) * MM + bc4);
    }
    __syncthreads();
    #pragma unroll 8
    for (int kk = 0; kk < TK1; ++kk) {
      const float a0 = sA[ty4 + 0][kk];
      const float a1 = sA[ty4 + 1][kk];
      const float a2 = sA[ty4 + 2][kk];
      const float a3 = sA[ty4 + 3][kk];
      const float4 b = *(const float4*)&sB[kk][tx4];
      acc[0][0] = fmaf(a0, b.x, acc[0][0]); acc[0][1] = fmaf(a0, b.y, acc[0][1]);
      acc[0][2] = fmaf(a0, b.z, acc[0][2]); acc[0][3] = fmaf(a0, b.w, acc[0][3]);
      acc[1][0] = fmaf(a1, b.x, acc[1][0]); acc[1][1] = fmaf(a1, b.y, acc[1][1]);
      acc[1][2] = fmaf(a1, b.z, acc[1][2]); acc[1][3] = fmaf(a1, b.w, acc[1][3]);
      acc[2][0] = fmaf(a2, b.x, acc[2][0]); acc[2][1] = fmaf(a2, b.y, acc[2][1]);
      acc[2][2] = fmaf(a2, b.z, acc[2][2]); acc[2][3] = fmaf(a2, b.w, acc[2][3]);
      acc[3][0] = fmaf(a3, b.x, acc[3][0]); acc[3][1] = fmaf(a3, b.y, acc[3][1]);
      acc[3][2] = fmaf(a3, b.z, acc[3][2]); acc[3][3] = fmaf(a3, b.w, acc[3][3]);
    }
    __syncthreads();
  }

  const float4 bv = *(const float4*)(dec_b + (size_t)p * MM + n0 + tx4);
  #pragma unroll
  for (int i = 0; i < 4; ++i) {
    if (tO[i] >= 0) {
      float4 o;
      o.x = acc[i][0] + bv.x; o.y = acc[i][1] + bv.y;
      o.z = acc[i][2] + bv.z; o.w = acc[i][3] + bv.w;
      *(float4*)(logits + (size_t)tO[i] * MM + n0 + tx4) = o;
    }
  }
}

// ---------------- K2: per-token softmax / entropy / gumbel / argmax ----------------
__device__ __forceinline__ float wred_max(float v) {
  #pragma unroll
  for (int o = 32; o > 0; o >>= 1) v = fmaxf(v, __shfl_xor(v, o));
  return v;
}
__device__ __forceinline__ float wred_sum(float v) {
  #pragma unroll
  for (int o = 32; o > 0; o >>= 1) v += __shfl_xor(v, o);
  return v;
}

__global__ __launch_bounds__(256) void k_softmax(
    const int* __restrict__ inp_word, const int* __restrict__ inp_pos,
    const int* __restrict__ inp_mask, const float* __restrict__ u_gum,
    const int* __restrict__ words,
    const float* __restrict__ psr_w, const float* __restrict__ atk_w,
    float* __restrict__ spt, float* __restrict__ entsum,
    float* __restrict__ out)
{
  const int t = blockIdx.x;
  const int tid = threadIdx.x;
  const int p = inp_pos[t];
  const int w_in = inp_word[t];
  const int msk = inp_mask[t];

  if (p >= NEXP) {
    // copy-through token
    if (tid < DD / 4) {
      const float4* pr = (const float4*)(psr_w + (size_t)w_in * DD);
      const float4* aw = (const float4*)(atk_w + (size_t)w_in * DD);
      ((float4*)(out + OFF_PSR + (size_t)t * DD))[tid] = pr[tid];
      ((float4*)(out + OFF_ATK + (size_t)t * DD))[tid] = aw[tid];
    }
    if (tid == 0) {
      out[OFF_WORD + t] = (float)w_in;
      out[OFF_CPY + t] = (msk != 0) ? 1.f : 0.f;  // obf_word == inp_word here
      out[OFF_OBF + t] = 0.f;
      out[OFF_PRI + t] = 0.f;
    }
    return;
  }

  float* lg = spt + (size_t)t * MM;
  const float4 l4 = *(const float4*)(lg + tid * 4);
  float l[4] = {l4.x, l4.y, l4.z, l4.w};

  __shared__ float sred[4];
  __shared__ float svv[4];
  __shared__ int   svi[4];

  // block max of logits
  float v = fmaxf(fmaxf(l[0], l[1]), fmaxf(l[2], l[3]));
  v = wred_max(v);
  if ((tid & 63) == 0) sred[tid >> 6] = v;
  __syncthreads();
  const float lmax = fmaxf(fmaxf(sred[0], sred[1]), fmaxf(sred[2], sred[3]));

  // sum exp
  float e[4], ls = 0.f;
  #pragma unroll
  for (int j = 0; j < 4; ++j) { e[j] = expf(l[j] - lmax); ls += e[j]; }
  ls = wred_sum(ls);
  __syncthreads();
  if ((tid & 63) == 0) sred[tid >> 6] = ls;
  __syncthreads();
  const float s1 = sred[0] + sred[1] + sred[2] + sred[3];
  const float lse = logf(s1);

  // entropy partial: sum pspt * exp(pspt)
  float pe = 0.f;
  #pragma unroll
  for (int j = 0; j < 4; ++j) pe += (l[j] - lmax - lse) * e[j];
  pe = wred_sum(pe);
  __syncthreads();
  if ((tid & 63) == 0) sred[tid >> 6] = pe;
  __syncthreads();
  if (tid == 0) {
    const float tot = (sred[0] + sred[1] + sred[2] + sred[3]) / s1;
    atomicAdd(&entsum[p], -tot);  // neg_ent (positive)
  }

  // gumbel perturbation: z = logits + g  (same argmax/softmax as pspt + g)
  const float4 u4 = *(const float4*)(u_gum + (size_t)t * MM + tid * 4);
  float uu[4] = {u4.x, u4.y, u4.z, u4.w};
  float z[4];
  #pragma unroll
  for (int j = 0; j < 4; ++j) {
    float u = fminf(fmaxf(uu[j], 1e-6f), 1.0f - 1e-6f);
    z[j] = l[j] - logf(-logf(u));
  }

  // block argmax with lowest-index tie-break (matches jnp.argmax)
  float zv = z[0]; int zi = tid * 4;
  #pragma unroll
  for (int j = 1; j < 4; ++j) { if (z[j] > zv) { zv = z[j]; zi = tid * 4 + j; } }
  #pragma unroll
  for (int o = 32; o > 0; o >>= 1) {
    float ov = __shfl_xor(zv, o);
    int   oi = __shfl_xor(zi, o);
    if (ov > zv || (ov == zv && oi < zi)) { zv = ov; zi = oi; }
  }
  if ((tid & 63) == 0) { svv[tid >> 6] = zv; svi[tid >> 6] = zi; }
  __syncthreads();
  float fv = svv[0]; int fi = svi[0];
  #pragma unroll
  for (int q = 1; q < 4; ++q) {
    if (svv[q] > fv || (svv[q] == fv && svi[q] < fi)) { fv = svv[q]; fi = svi[q]; }
  }

  // softmax(z) -> spt, written in place over logits
  float e2[4], ls2 = 0.f;
  #pragma unroll
  for (int j = 0; j < 4; ++j) { e2[j] = expf(z[j] - fv); ls2 += e2[j]; }
  ls2 = wred_sum(ls2);
  __syncthreads();
  if ((tid & 63) == 0) sred[tid >> 6] = ls2;
  __syncthreads();
  const float s2 = sred[0] + sred[1] + sred[2] + sred[3];

  float4 o4;
  o4.x = e2[0] / s2; o4.y = e2[1] / s2; o4.z = e2[2] / s2; o4.w = e2[3] / s2;
  *(float4*)(lg + tid * 4) = o4;

  if (tid == 0) {
    const int wsel = words[p * MM + fi];
    out[OFF_WORD + t] = (float)wsel;
    out[OFF_CPY + t] = ((wsel == w_in) && (msk != 0)) ? 1.f : 0.f;
    out[OFF_OBF + t] = 1.f;
    out[OFF_PRI + t] = (p < NPRIV) ? 1.f : 0.f;
  }
}

// ---------------- K3: per-expert embed GEMMs  psr/atk = spt_sel @ LUT_p ----------------
#define TM3 32
#define TN3 64
#define TK3 64

__global__ __launch_bounds__(256) void k_embed(
    const float* __restrict__ spt, const int* __restrict__ words,
    const float* __restrict__ psr_w, const float* __restrict__ atk_w,
    const int* __restrict__ toklist, const int* __restrict__ cnt,
    float* __restrict__ out)
{
  const int p = blockIdx.z;
  const int ncnt = cnt[p];
  const int row0 = blockIdx.y * TM3;
  if (row0 >= ncnt) return;
  const int n0 = blockIdx.x * TN3;
  const int tid = threadIdx.x;

  __shared__ float sS[TM3][TK3 + 1];
  __shared__ float sP[TK3][68];   // 68-stride: 16B-aligned rows, bank-spread
  __shared__ float sAk[TK3][68];

  const int tx = tid & 15, ty = tid >> 4;
  const int tx4 = tx * 4, ty2 = ty * 2;

  const int ar = tid >> 3;
  const int ac0 = (tid & 7) * 8;
  int tS = -1;
  if (row0 + ar < ncnt) tS = toklist[p * TT + row0 + ar];

  const int lr = tid >> 4;        // 0..15
  const int lc4 = (tid & 15) * 4; // 0..60

  int tO[2];
  #pragma unroll
  for (int i = 0; i < 2; ++i) {
    int rr = row0 + ty2 + i;
    tO[i] = (rr < ncnt) ? toklist[p * TT + rr] : -1;
  }

  float ap[2][4] = {};
  float aa[2][4] = {};

  for (int m0 = 0; m0 < MM; m0 += TK3) {
    if (tS >= 0) {
      const float* src = spt + (size_t)tS * MM + m0 + ac0;
      #pragma unroll
      for (int j = 0; j < 8; ++j) sS[ar][ac0 + j] = src[j];
    } else {
      #pragma unroll
      for (int j = 0; j < 8; ++j) sS[ar][ac0 + j] = 0.f;
    }
    #pragma unroll
    for (int j = 0; j < 4; ++j) {
      const int r = lr + j * 16;
      const int w = words[p * MM + m0 + r];
      *(float4*)&sP[r][lc4]  = *(const float4*)(psr_w + (size_t)w * DD + n0 + lc4);
      *(float4*)&sAk[r][lc4] = *(const float4*)(atk_w + (size_t)w * DD + n0 + lc4);
    }
    __syncthreads();
    #pragma unroll 8
    for (int kk = 0; kk < TK3; ++kk) {
      const float s0 = sS[ty2 + 0][kk];
      const float s1 = sS[ty2 + 1][kk];
      const float4 pv = *(const float4*)&sP[kk][tx4];
      const float4 av = *(const float4*)&sAk[kk][tx4];
      ap[0][0] = fmaf(s0, pv.x, ap[0][0]); ap[0][1] = fmaf(s0, pv.y, ap[0][1]);
      ap[0][2] = fmaf(s0, pv.z, ap[0][2]); ap[0][3] = fmaf(s0, pv.w, ap[0][3]);
      ap[1][0] = fmaf(s1, pv.x, ap[1][0]); ap[1][1] = fmaf(s1, pv.y, ap[1][1]);
      ap[1][2] = fmaf(s1, pv.z, ap[1][2]); ap[1][3] = fmaf(s1, pv.w, ap[1][3]);
      aa[0][0] = fmaf(s0, av.x, aa[0][0]); aa[0][1] = fmaf(s0, av.y, aa[0][1]);
      aa[0][2] = fmaf(s0, av.z, aa[0][2]); aa[0][3] = fmaf(s0, av.w, aa[0][3]);
      aa[1][0] = fmaf(s1, av.x, aa[1][0]); aa[1][1] = fmaf(s1, av.y, aa[1][1]);
      aa[1][2] = fmaf(s1, av.z, aa[1][2]); aa[1][3] = fmaf(s1, av.w, aa[1][3]);
    }
    __syncthreads();
  }

  #pragma unroll
  for (int i = 0; i < 2; ++i) {
    if (tO[i] >= 0) {
      *(float4*)(out + OFF_PSR + (size_t)tO[i] * DD + n0 + tx4) =
          make_float4(ap[i][0], ap[i][1], ap[i][2], ap[i][3]);
      *(float4*)(out + OFF_ATK + (size_t)tO[i] * DD + n0 + tx4) =
          make_float4(aa[i][0], aa[i][1], aa[i][2], aa[i][3]);
    }
  }
}

// ---------------- K4: entropy finalization ----------------
__global__ void k_finalize(const float* __restrict__ entsum,
                           const int* __restrict__ cnt, float* __restrict__ out)
{
  if (threadIdx.x == 0 && blockIdx.x == 0) {
    float s = 0.f;
    for (int p = 0; p < NEXP; ++p) {
      int n = cnt[p];
      if (n > 0) s += entsum[p] / ((float)n * (float)MM);
    }
    out[OFF_ENT] = -s;  // ent_loss = -entropy
  }
}

extern "C" void kernel_launch(void* const* d_in, const int* in_sizes, int n_in,
                              void* d_out, int out_size, void* d_ws, size_t ws_size,
                              hipStream_t stream)
{
  (void)in_sizes; (void)n_in; (void)out_size; (void)ws_size;

  const int*   inp_word = (const int*)d_in[0];
  const int*   inp_pos  = (const int*)d_in[1];
  const int*   inp_mask = (const int*)d_in[2];
  const float* ctx      = (const float*)d_in[3];
  const float* dec_W    = (const float*)d_in[4];
  const float* dec_b    = (const float*)d_in[5];
  const float* psr_w    = (const float*)d_in[6];
  const float* atk_w    = (const float*)d_in[7];
  const int*   words    = (const int*)d_in[8];
  const float* u_gum    = (const float*)d_in[9];

  float* out = (float*)d_out;
  char*  ws  = (char*)d_ws;
  float* spt     = (float*)(ws + WS_SPT);
  int*   toklist = (int*)(ws + WS_TOKLIST);
  int*   cnt     = (int*)(ws + WS_CNT);
  float* entsum  = (float*)(ws + WS_ENTSUM);

  hipMemsetAsync(ws + WS_CNT, 0, NEXP * 4 * 2, stream);
  k_bucket<<<TT / 256, 256, 0, stream>>>(inp_pos, toklist, cnt);
  k_decode<<<dim3(MM / TN1, TT / TM1, NEXP), 256, 0, stream>>>(
      ctx, dec_W, dec_b, toklist, cnt, spt);
  k_softmax<<<TT, 256, 0, stream>>>(
      inp_word, inp_pos, inp_mask, u_gum, words, psr_w, atk_w, spt, entsum, out);
  k_embed<<<dim3(DD / TN3, TT / TM3, NEXP), 256, 0, stream>>>(
      spt, words, psr_w, atk_w, toklist, cnt, out);
  k_finalize<<<1, 64, 0, stream>>>(entsum, cnt, out);
}